// Round 1
// baseline (231.905 us; speedup 1.0000x reference)
//
#include <hip/hip_runtime.h>
#include <hip/hip_bf16.h>

// BatchTripletLoss on MI355X.
// Strategy: rowmax_i over j != i of (c[j] - 2*dot(x_i,x_j)), c[j] = sq[j]-2*eps*sum[j],
// via fused bf16-MFMA GEMM (m97 structure: 128x128 tile, BK=64, global_load_lds w=16).
// Row stats (sq, sum, pos_dist, valid) computed exactly in f32.
// d2 = rowmax + (sq[i]+2*eps*sum[i]+d*eps^2); loss = relu(pos_dist - sqrt(max(d2,0)) + margin).

#define NROWS 8192
#define DIM   1024
#define BM 128
#define BN 128
#define BK 64

constexpr float EPS = 1e-6f;
constexpr float MARGIN = 0.5f;

typedef __attribute__((ext_vector_type(8))) short short8;
typedef __attribute__((ext_vector_type(4))) float f32x4;

__device__ __forceinline__ unsigned short f2bf_rne(float f) {
    unsigned u = __float_as_uint(f);
    u += 0x7fffu + ((u >> 16) & 1u);
    return (unsigned short)(u >> 16);
}

// ---------------- kernel 1: per-row stats + bf16 conversion ----------------
// one wave per row (4 rows / 256-thread block)
__global__ void prep_kernel(const float* __restrict__ X, const float* __restrict__ P,
                            unsigned short* __restrict__ Xb,
                            float* __restrict__ cj, float* __restrict__ basei,
                            float* __restrict__ posd, int* __restrict__ valid)
{
    const int tid  = threadIdx.x;
    const int w    = tid >> 6;
    const int lane = tid & 63;
    const int row  = blockIdx.x * 4 + w;
    const float* xr = X + (size_t)row * DIM;

    float sq = 0.f, sm = 0.f, pd = 0.f;
    bool eq = true;
    #pragma unroll
    for (int it = 0; it < 4; ++it) {
        const int idx = it * 256 + lane * 4;
        const float4 x = *(const float4*)(xr + idx);
        const float4 p = *(const float4*)(P + idx);
        sq += x.x*x.x + x.y*x.y + x.z*x.z + x.w*x.w;
        sm += x.x + x.y + x.z + x.w;
        const float d0 = x.x - p.x + EPS, d1 = x.y - p.y + EPS;
        const float d2 = x.z - p.z + EPS, d3 = x.w - p.w + EPS;
        pd += d0*d0 + d1*d1 + d2*d2 + d3*d3;
        eq = eq && (x.x == p.x) && (x.y == p.y) && (x.z == p.z) && (x.w == p.w);
        ushort4 b;
        b.x = f2bf_rne(x.x); b.y = f2bf_rne(x.y); b.z = f2bf_rne(x.z); b.w = f2bf_rne(x.w);
        *(ushort4*)(Xb + (size_t)row * DIM + idx) = b;
    }
    #pragma unroll
    for (int off = 32; off >= 1; off >>= 1) {
        sq += __shfl_xor(sq, off);
        sm += __shfl_xor(sm, off);
        pd += __shfl_xor(pd, off);
    }
    const bool alleq = __all(eq);
    if (lane == 0) {
        cj[row]    = sq - 2.f * EPS * sm;
        basei[row] = sq + 2.f * EPS * sm + (float)DIM * EPS * EPS;
        posd[row]  = sqrtf(pd);
        valid[row] = alleq ? 0 : 1;
    }
}

// ---------------- kernel 2: fused GEMM + row-max ----------------
// 128x128 output tile / block, 4 waves (2x2), each wave 64x64 = 4x4 frags of 16x16x32 bf16 MFMA.
__global__ __launch_bounds__(256) void gemm_max_kernel(
        const unsigned short* __restrict__ Xb,
        const float* __restrict__ cj,
        float* __restrict__ partmax)
{
    __shared__ alignas(16) unsigned short As[BM * BK];
    __shared__ alignas(16) unsigned short Bs[BN * BK];
    __shared__ float partrow[2][BM];

    const int tid  = threadIdx.x;
    const int lane = tid & 63;
    const int w    = tid >> 6;
    const int wm   = w >> 1, wn = w & 1;
    const int bn = blockIdx.x, bm = blockIdx.y;
    const int Mbase = bm * BM, Nbase = bn * BN;

    f32x4 acc[4][4];
    #pragma unroll
    for (int m = 0; m < 4; ++m)
        #pragma unroll
        for (int n = 0; n < 4; ++n)
            acc[m][n] = (f32x4){0.f, 0.f, 0.f, 0.f};

    const int chunk_base = w * 64 + lane;

    for (int kt = 0; kt < DIM / BK; ++kt) {
        const int k0 = kt * BK;
        // stage A (BM x BK) and B (BN x BK), row-major, linear LDS dest (wave-uniform base)
        #pragma unroll
        for (int i = 0; i < 4; ++i) {
            const int chunk = i * 256 + chunk_base;      // 0..1023, 16B each
            const int r  = chunk >> 3;                   // row in tile
            const int c8 = chunk & 7;                    // 8-elem group in row
            const unsigned short* srcA = Xb + (size_t)(Mbase + r) * DIM + k0 + c8 * 8;
            const unsigned short* srcB = Xb + (size_t)(Nbase + r) * DIM + k0 + c8 * 8;
            unsigned short* dstA = As + (i * 256 + w * 64) * 8;   // wave-uniform
            unsigned short* dstB = Bs + (i * 256 + w * 64) * 8;
            __builtin_amdgcn_global_load_lds((const __attribute__((address_space(1))) void*)srcA,
                                             (__attribute__((address_space(3))) void*)dstA, 16, 0, 0);
            __builtin_amdgcn_global_load_lds((const __attribute__((address_space(1))) void*)srcB,
                                             (__attribute__((address_space(3))) void*)dstB, 16, 0, 0);
        }
        __syncthreads();

        #pragma unroll
        for (int ks = 0; ks < 2; ++ks) {
            const int kk = ks * 32 + (lane >> 4) * 8;
            short8 a[4], b[4];
            #pragma unroll
            for (int m = 0; m < 4; ++m)
                a[m] = *(const short8*)(As + (wm * 64 + m * 16 + (lane & 15)) * BK + kk);
            #pragma unroll
            for (int n = 0; n < 4; ++n)
                b[n] = *(const short8*)(Bs + (wn * 64 + n * 16 + (lane & 15)) * BK + kk);
            #pragma unroll
            for (int m = 0; m < 4; ++m)
                #pragma unroll
                for (int n = 0; n < 4; ++n)
                    acc[m][n] = __builtin_amdgcn_mfma_f32_16x16x32_bf16(a[m], b[n], acc[m][n], 0, 0, 0);
        }
        __syncthreads();
    }

    // epilogue: val = c[j] - 2*dot; exclude diagonal; row-max across this block's 128 cols.
    // C/D layout (verified m89/m91): col = lane&15, row = (lane>>4)*4 + reg.
    float cv[4];
    #pragma unroll
    for (int n = 0; n < 4; ++n)
        cv[n] = cj[Nbase + wn * 64 + n * 16 + (lane & 15)];

    const int lrow0 = wm * 64 + ((lane >> 4) << 2);     // + m*16 + r
    const int gcol0 = Nbase + wn * 64 + (lane & 15);    // + n*16

    #pragma unroll
    for (int m = 0; m < 4; ++m) {
        #pragma unroll
        for (int r = 0; r < 4; ++r) {
            const int grow = Mbase + lrow0 + m * 16 + r;
            float v = -__builtin_inff();
            #pragma unroll
            for (int n = 0; n < 4; ++n) {
                float val = cv[n] - 2.f * acc[m][n][r];
                if (grow == gcol0 + n * 16) val = -__builtin_inff();  // j == i
                v = fmaxf(v, val);
            }
            #pragma unroll
            for (int off = 8; off >= 1; off >>= 1)
                v = fmaxf(v, __shfl_xor(v, off));      // reduce 16 cols
            if ((lane & 15) == 0)
                partrow[wn][lrow0 + m * 16 + r] = v;
        }
    }
    __syncthreads();
    if (tid < BM) {
        const float v = fmaxf(partrow[0][tid], partrow[1][tid]);
        partmax[(size_t)bn * NROWS + Mbase + tid] = v;
    }
}

// ---------------- kernel 3: per-row finalize + block partial sums ----------------
__global__ void finalize1_kernel(const float* __restrict__ partmax,
                                 const float* __restrict__ basei,
                                 const float* __restrict__ posd,
                                 const int* __restrict__ valid,
                                 float* __restrict__ partials)
{
    const int tid = threadIdx.x;
    const int row = blockIdx.x * 256 + tid;
    float m = -__builtin_inff();
    #pragma unroll 8
    for (int p = 0; p < 64; ++p)
        m = fmaxf(m, partmax[(size_t)p * NROWS + row]);
    const float d2 = m + basei[row];
    const float mn = sqrtf(fmaxf(d2, 0.f));
    float loss = fmaxf(posd[row] - mn + MARGIN, 0.f);
    float cnt = 1.f;
    if (!valid[row]) { loss = 0.f; cnt = 0.f; }
    #pragma unroll
    for (int off = 32; off >= 1; off >>= 1) {
        loss += __shfl_xor(loss, off);
        cnt  += __shfl_xor(cnt, off);
    }
    __shared__ float sl[4], sc[4];
    const int w = tid >> 6, lane = tid & 63;
    if (lane == 0) { sl[w] = loss; sc[w] = cnt; }
    __syncthreads();
    if (tid == 0) {
        partials[blockIdx.x * 2]     = sl[0] + sl[1] + sl[2] + sl[3];
        partials[blockIdx.x * 2 + 1] = sc[0] + sc[1] + sc[2] + sc[3];
    }
}

// ---------------- kernel 4: final scalar ----------------
__global__ void finalize2_kernel(const float* __restrict__ partials, float* __restrict__ out)
{
    const int tid = threadIdx.x;   // 64 threads
    float l = 0.f, c = 0.f;
    if (tid < 32) { l = partials[tid * 2]; c = partials[tid * 2 + 1]; }
    #pragma unroll
    for (int off = 32; off >= 1; off >>= 1) {
        l += __shfl_xor(l, off);
        c += __shfl_xor(c, off);
    }
    if (tid == 0) out[0] = l / c;
}

extern "C" void kernel_launch(void* const* d_in, const int* in_sizes, int n_in,
                              void* d_out, int out_size, void* d_ws, size_t ws_size,
                              hipStream_t stream)
{
    const float* X = (const float*)d_in[0];   // [8192,1024] f32
    const float* P = (const float*)d_in[1];   // [1024] f32
    float* out = (float*)d_out;
    char* ws = (char*)d_ws;

    // ws layout (~19.1 MB total)
    unsigned short* Xb = (unsigned short*)ws;                                // 16 MB bf16
    size_t off = (size_t)NROWS * DIM * sizeof(unsigned short);
    float* cj    = (float*)(ws + off);  off += (size_t)NROWS * 4;
    float* basei = (float*)(ws + off);  off += (size_t)NROWS * 4;
    float* posd  = (float*)(ws + off);  off += (size_t)NROWS * 4;
    int*   valid = (int*)(ws + off);    off += (size_t)NROWS * 4;
    float* partmax = (float*)(ws + off); off += (size_t)64 * NROWS * 4;      // 2 MB
    float* partials = (float*)(ws + off);                                    // 32*2 f32

    prep_kernel<<<NROWS / 4, 256, 0, stream>>>(X, P, Xb, cj, basei, posd, valid);
    dim3 grid(NROWS / BN, NROWS / BM);
    gemm_max_kernel<<<grid, 256, 0, stream>>>(Xb, cj, partmax);
    finalize1_kernel<<<NROWS / 256, 256, 0, stream>>>(partmax, basei, posd, valid, partials);
    finalize2_kernel<<<1, 64, 0, stream>>>(partials, out);
}

// Round 2
// 155.132 us; speedup vs baseline: 1.4949x; 1.4949x over previous
//
#include <hip/hip_runtime.h>
#include <hip/hip_bf16.h>

// BatchTripletLoss on MI355X — round 2: symmetric halving.
// rowmax_i over j != i of (c[j] - 2*dot(x_i,x_j)), c[j] = sq[j]-2*eps*sum[j].
// dot is symmetric -> compute only upper-triangular 128x128 blocks (bn >= bm).
// Epilogue extracts BOTH row-max (M-tile rows over N cols) and col-max
// (N-tile rows over M cols, using c[row in M]); diagonal blocks mask i==j and
// skip the transposed pass. Slot coverage: row-block B gets slot p>=B from
// block (B,p) row-path, slot p<B from block (p,B) transposed-path — exactly once.

#define NROWS 8192
#define DIM   1024
#define BM 128
#define BN 128
#define BK 64

constexpr float EPS = 1e-6f;
constexpr float MARGIN = 0.5f;

typedef __attribute__((ext_vector_type(8))) short short8;
typedef __attribute__((ext_vector_type(4))) float f32x4;

__device__ __forceinline__ unsigned short f2bf_rne(float f) {
    unsigned u = __float_as_uint(f);
    u += 0x7fffu + ((u >> 16) & 1u);
    return (unsigned short)(u >> 16);
}

// ---------------- kernel 1: per-row stats + bf16 conversion ----------------
__global__ void prep_kernel(const float* __restrict__ X, const float* __restrict__ P,
                            unsigned short* __restrict__ Xb,
                            float* __restrict__ cj, float* __restrict__ basei,
                            float* __restrict__ posd, int* __restrict__ valid)
{
    const int tid  = threadIdx.x;
    const int w    = tid >> 6;
    const int lane = tid & 63;
    const int row  = blockIdx.x * 4 + w;
    const float* xr = X + (size_t)row * DIM;

    float sq = 0.f, sm = 0.f, pd = 0.f;
    bool eq = true;
    #pragma unroll
    for (int it = 0; it < 4; ++it) {
        const int idx = it * 256 + lane * 4;
        const float4 x = *(const float4*)(xr + idx);
        const float4 p = *(const float4*)(P + idx);
        sq += x.x*x.x + x.y*x.y + x.z*x.z + x.w*x.w;
        sm += x.x + x.y + x.z + x.w;
        const float d0 = x.x - p.x + EPS, d1 = x.y - p.y + EPS;
        const float d2 = x.z - p.z + EPS, d3 = x.w - p.w + EPS;
        pd += d0*d0 + d1*d1 + d2*d2 + d3*d3;
        eq = eq && (x.x == p.x) && (x.y == p.y) && (x.z == p.z) && (x.w == p.w);
        ushort4 b;
        b.x = f2bf_rne(x.x); b.y = f2bf_rne(x.y); b.z = f2bf_rne(x.z); b.w = f2bf_rne(x.w);
        *(ushort4*)(Xb + (size_t)row * DIM + idx) = b;
    }
    #pragma unroll
    for (int off = 32; off >= 1; off >>= 1) {
        sq += __shfl_xor(sq, off);
        sm += __shfl_xor(sm, off);
        pd += __shfl_xor(pd, off);
    }
    const bool alleq = __all(eq);
    if (lane == 0) {
        cj[row]    = sq - 2.f * EPS * sm;
        basei[row] = sq + 2.f * EPS * sm + (float)DIM * EPS * EPS;
        posd[row]  = sqrtf(pd);
        valid[row] = alleq ? 0 : 1;
    }
}

// ---------------- kernel 2: fused symmetric GEMM + row/col max ----------------
__global__ __launch_bounds__(256) void gemm_max_kernel(
        const unsigned short* __restrict__ Xb,
        const float* __restrict__ cj,
        float* __restrict__ partmax)
{
    __shared__ alignas(16) unsigned short As[BM * BK];
    __shared__ alignas(16) unsigned short Bs[BN * BK];
    __shared__ float partrow[2][BM];
    __shared__ float partcol[2][BN];

    const int tid  = threadIdx.x;
    const int lane = tid & 63;
    const int w    = tid >> 6;
    const int wm   = w >> 1, wn = w & 1;

    // triangular decode: t -> (bm, bn), bn >= bm; base(b) = (129*b - b*b)/2
    const int t = blockIdx.x;
    int bm = (int)((129.0f - sqrtf(16641.0f - 8.0f * (float)t)) * 0.5f);
    if (bm > 63) bm = 63;
    if (bm < 0) bm = 0;
    while (bm > 0 && (129 * bm - bm * bm) / 2 > t) --bm;
    while ((129 * (bm + 1) - (bm + 1) * (bm + 1)) / 2 <= t) ++bm;
    const int bn = bm + (t - (129 * bm - bm * bm) / 2);
    const bool diag = (bm == bn);
    const int Mbase = bm * BM, Nbase = bn * BN;

    f32x4 acc[4][4];
    #pragma unroll
    for (int m = 0; m < 4; ++m)
        #pragma unroll
        for (int n = 0; n < 4; ++n)
            acc[m][n] = (f32x4){0.f, 0.f, 0.f, 0.f};

    const int chunk_base = w * 64 + lane;

    for (int kt = 0; kt < DIM / BK; ++kt) {
        const int k0 = kt * BK;
        #pragma unroll
        for (int i = 0; i < 4; ++i) {
            const int chunk = i * 256 + chunk_base;      // 0..1023, 16B each
            const int r  = chunk >> 3;
            const int c8 = chunk & 7;
            const unsigned short* srcA = Xb + (size_t)(Mbase + r) * DIM + k0 + c8 * 8;
            const unsigned short* srcB = Xb + (size_t)(Nbase + r) * DIM + k0 + c8 * 8;
            unsigned short* dstA = As + (i * 256 + w * 64) * 8;
            unsigned short* dstB = Bs + (i * 256 + w * 64) * 8;
            __builtin_amdgcn_global_load_lds((const __attribute__((address_space(1))) void*)srcA,
                                             (__attribute__((address_space(3))) void*)dstA, 16, 0, 0);
            __builtin_amdgcn_global_load_lds((const __attribute__((address_space(1))) void*)srcB,
                                             (__attribute__((address_space(3))) void*)dstB, 16, 0, 0);
        }
        __syncthreads();

        #pragma unroll
        for (int ks = 0; ks < 2; ++ks) {
            const int kk = ks * 32 + (lane >> 4) * 8;
            short8 a[4], b[4];
            #pragma unroll
            for (int m = 0; m < 4; ++m)
                a[m] = *(const short8*)(As + (wm * 64 + m * 16 + (lane & 15)) * BK + kk);
            #pragma unroll
            for (int n = 0; n < 4; ++n)
                b[n] = *(const short8*)(Bs + (wn * 64 + n * 16 + (lane & 15)) * BK + kk);
            #pragma unroll
            for (int m = 0; m < 4; ++m)
                #pragma unroll
                for (int n = 0; n < 4; ++n)
                    acc[m][n] = __builtin_amdgcn_mfma_f32_16x16x32_bf16(a[m], b[n], acc[m][n], 0, 0, 0);
        }
        __syncthreads();
    }

    // ---- epilogue. C/D layout: col = lane&15, row = (lane>>4)*4 + reg.
    const int lrow0 = wm * 64 + ((lane >> 4) << 2);     // + m*16 + r
    const int lcol0 = wn * 64 + (lane & 15);            // + n*16
    const int gcol0 = Nbase + lcol0;

    // (a) row-max: rows of M-tile over this block's 128 N-cols
    float cv[4];
    #pragma unroll
    for (int n = 0; n < 4; ++n)
        cv[n] = cj[gcol0 + n * 16];

    #pragma unroll
    for (int m = 0; m < 4; ++m) {
        #pragma unroll
        for (int r = 0; r < 4; ++r) {
            const int grow = Mbase + lrow0 + m * 16 + r;
            float v = -__builtin_inff();
            #pragma unroll
            for (int n = 0; n < 4; ++n) {
                float val = cv[n] - 2.f * acc[m][n][r];
                if (diag && grow == gcol0 + n * 16) val = -__builtin_inff();
                v = fmaxf(v, val);
            }
            #pragma unroll
            for (int off = 8; off >= 1; off >>= 1)
                v = fmaxf(v, __shfl_xor(v, off));
            if ((lane & 15) == 0)
                partrow[wn][lrow0 + m * 16 + r] = v;
        }
    }

    // (b) transposed col-max: rows of N-tile over this block's 128 M-cols
    if (!diag) {
        float vt[4];
        #pragma unroll
        for (int n = 0; n < 4; ++n) vt[n] = -__builtin_inff();
        #pragma unroll
        for (int m = 0; m < 4; ++m) {
            #pragma unroll
            for (int r = 0; r < 4; ++r) {
                const float ci = cj[Mbase + lrow0 + m * 16 + r];
                #pragma unroll
                for (int n = 0; n < 4; ++n)
                    vt[n] = fmaxf(vt[n], ci - 2.f * acc[m][n][r]);
            }
        }
        // reduce across the four lane>>4 groups (same lane&15 = same column)
        #pragma unroll
        for (int n = 0; n < 4; ++n) {
            vt[n] = fmaxf(vt[n], __shfl_xor(vt[n], 16));
            vt[n] = fmaxf(vt[n], __shfl_xor(vt[n], 32));
            if ((lane >> 4) == 0)
                partcol[wm][lcol0 + n * 16] = vt[n];
        }
    }
    __syncthreads();

    if (tid < BM) {
        const float v = fmaxf(partrow[0][tid], partrow[1][tid]);
        partmax[(size_t)bn * NROWS + Mbase + tid] = v;
    } else if (!diag) {
        const int c = tid - 128;
        const float v = fmaxf(partcol[0][c], partcol[1][c]);
        partmax[(size_t)bm * NROWS + Nbase + c] = v;
    }
}

// ---------------- kernel 3: per-row finalize + block partial sums ----------------
__global__ void finalize1_kernel(const float* __restrict__ partmax,
                                 const float* __restrict__ basei,
                                 const float* __restrict__ posd,
                                 const int* __restrict__ valid,
                                 float* __restrict__ partials)
{
    const int tid = threadIdx.x;
    const int row = blockIdx.x * 256 + tid;
    float m = -__builtin_inff();
    #pragma unroll 8
    for (int p = 0; p < 64; ++p)
        m = fmaxf(m, partmax[(size_t)p * NROWS + row]);
    const float d2 = m + basei[row];
    const float mn = sqrtf(fmaxf(d2, 0.f));
    float loss = fmaxf(posd[row] - mn + MARGIN, 0.f);
    float cnt = 1.f;
    if (!valid[row]) { loss = 0.f; cnt = 0.f; }
    #pragma unroll
    for (int off = 32; off >= 1; off >>= 1) {
        loss += __shfl_xor(loss, off);
        cnt  += __shfl_xor(cnt, off);
    }
    __shared__ float sl[4], sc[4];
    const int w = tid >> 6, lane = tid & 63;
    if (lane == 0) { sl[w] = loss; sc[w] = cnt; }
    __syncthreads();
    if (tid == 0) {
        partials[blockIdx.x * 2]     = sl[0] + sl[1] + sl[2] + sl[3];
        partials[blockIdx.x * 2 + 1] = sc[0] + sc[1] + sc[2] + sc[3];
    }
}

// ---------------- kernel 4: final scalar ----------------
__global__ void finalize2_kernel(const float* __restrict__ partials, float* __restrict__ out)
{
    const int tid = threadIdx.x;   // 64 threads
    float l = 0.f, c = 0.f;
    if (tid < 32) { l = partials[tid * 2]; c = partials[tid * 2 + 1]; }
    #pragma unroll
    for (int off = 32; off >= 1; off >>= 1) {
        l += __shfl_xor(l, off);
        c += __shfl_xor(c, off);
    }
    if (tid == 0) out[0] = l / c;
}

extern "C" void kernel_launch(void* const* d_in, const int* in_sizes, int n_in,
                              void* d_out, int out_size, void* d_ws, size_t ws_size,
                              hipStream_t stream)
{
    const float* X = (const float*)d_in[0];   // [8192,1024] f32
    const float* P = (const float*)d_in[1];   // [1024] f32
    float* out = (float*)d_out;
    char* ws = (char*)d_ws;

    unsigned short* Xb = (unsigned short*)ws;                                // 16 MB bf16
    size_t off = (size_t)NROWS * DIM * sizeof(unsigned short);
    float* cj    = (float*)(ws + off);  off += (size_t)NROWS * 4;
    float* basei = (float*)(ws + off);  off += (size_t)NROWS * 4;
    float* posd  = (float*)(ws + off);  off += (size_t)NROWS * 4;
    int*   valid = (int*)(ws + off);    off += (size_t)NROWS * 4;
    float* partmax = (float*)(ws + off); off += (size_t)64 * NROWS * 4;      // 2 MB
    float* partials = (float*)(ws + off);

    prep_kernel<<<NROWS / 4, 256, 0, stream>>>(X, P, Xb, cj, basei, posd, valid);
    const int nblocks = (64 * 65) / 2;   // 2080 upper-triangular 128x128 blocks
    gemm_max_kernel<<<nblocks, 256, 0, stream>>>(Xb, cj, partmax);
    finalize1_kernel<<<NROWS / 256, 256, 0, stream>>>(partmax, basei, posd, valid, partials);
    finalize2_kernel<<<1, 64, 0, stream>>>(partials, out);
}

// Round 3
// 137.838 us; speedup vs baseline: 1.6824x; 1.1255x over previous
//
#include <hip/hip_runtime.h>
#include <hip/hip_bf16.h>

// BatchTripletLoss on MI355X — round 3: symmetric 256^2 deep-pipelined MFMA GEMM.
// 8 waves (2x4), BK=32, 4 LDS buffers, prefetch depth 3, counted vmcnt(8),
// both-sides XOR swizzle (pre-swizzled global src + swizzled ds_read), XCD chunking,
// setprio around MFMA clusters. Triangular (bn>=bm) with row+col max epilogue.

#define NROWS 8192
#define DIM   1024
#define BT    256
#define BKQ   32
#define NT    (DIM / BKQ)          // 32 K-tiles
#define NBT   (NROWS / BT)         // 32 tile-rows
#define NTRI  (NBT * (NBT + 1) / 2) // 528 blocks

constexpr float EPS = 1e-6f;
constexpr float MARGIN = 0.5f;

typedef __attribute__((ext_vector_type(8))) short short8;
typedef __attribute__((ext_vector_type(4))) float f32x4;

__device__ __forceinline__ unsigned short f2bf_rne(float f) {
    unsigned u = __float_as_uint(f);
    u += 0x7fffu + ((u >> 16) & 1u);
    return (unsigned short)(u >> 16);
}

// ---------------- kernel 1: per-row stats + bf16 conversion ----------------
__global__ void prep_kernel(const float* __restrict__ X, const float* __restrict__ P,
                            unsigned short* __restrict__ Xb,
                            float* __restrict__ cj, float* __restrict__ basei,
                            float* __restrict__ posd, int* __restrict__ valid)
{
    const int tid  = threadIdx.x;
    const int w    = tid >> 6;
    const int lane = tid & 63;
    const int row  = blockIdx.x * 4 + w;
    const float* xr = X + (size_t)row * DIM;

    float sq = 0.f, sm = 0.f, pd = 0.f;
    bool eq = true;
    #pragma unroll
    for (int it = 0; it < 4; ++it) {
        const int idx = it * 256 + lane * 4;
        const float4 x = *(const float4*)(xr + idx);
        const float4 p = *(const float4*)(P + idx);
        sq += x.x*x.x + x.y*x.y + x.z*x.z + x.w*x.w;
        sm += x.x + x.y + x.z + x.w;
        const float d0 = x.x - p.x + EPS, d1 = x.y - p.y + EPS;
        const float d2 = x.z - p.z + EPS, d3 = x.w - p.w + EPS;
        pd += d0*d0 + d1*d1 + d2*d2 + d3*d3;
        eq = eq && (x.x == p.x) && (x.y == p.y) && (x.z == p.z) && (x.w == p.w);
        ushort4 b;
        b.x = f2bf_rne(x.x); b.y = f2bf_rne(x.y); b.z = f2bf_rne(x.z); b.w = f2bf_rne(x.w);
        *(ushort4*)(Xb + (size_t)row * DIM + idx) = b;
    }
    #pragma unroll
    for (int off = 32; off >= 1; off >>= 1) {
        sq += __shfl_xor(sq, off);
        sm += __shfl_xor(sm, off);
        pd += __shfl_xor(pd, off);
    }
    const bool alleq = __all(eq);
    if (lane == 0) {
        cj[row]    = sq - 2.f * EPS * sm;
        basei[row] = sq + 2.f * EPS * sm + (float)DIM * EPS * EPS;
        posd[row]  = sqrtf(pd);
        valid[row] = alleq ? 0 : 1;
    }
}

// ---------------- kernel 2: deep-pipelined symmetric GEMM + row/col max ----------------
// LDS chunk map (16B units, per 256x32 matrix tile): chunk q holds logical
// (row=q>>2, colchunk=(q&3)^((q>>4)&3)). Read addr for (row,c): row*4 + (c^((row>>2)&3)).
// For our reads (row = ..16m.. + l15, c = lk) the XOR term is (l15>>2) -> 2-way banks.
__global__ __launch_bounds__(512, 2) void gemm_max_kernel(
        const unsigned short* __restrict__ Xb,
        const float* __restrict__ cj,
        float* __restrict__ partmax)
{
    __shared__ alignas(16) unsigned short lds[4][16384];   // [buf][A:0..8191 | B:8192..16383]
    __shared__ float partrow[4][BT];
    __shared__ float partcol[2][BT];

    const int tid  = threadIdx.x;
    const int lane = tid & 63;
    const int wid  = tid >> 6;        // 0..7
    const int wm   = wid >> 2;        // 0..1  (M half: 128 rows)
    const int wn   = wid & 3;         // 0..3  (N quarter: 64 cols)
    const int l15  = lane & 15;
    const int lk   = lane >> 4;       // 0..3 (K chunk of 8)
    const int swz  = lk ^ (l15 >> 2);

    // XCD-chunked bijective triangular decode (528 = 8 * 66)
    const int t0 = (blockIdx.x & 7) * (NTRI / 8) + (blockIdx.x >> 3);
    int bm = (int)(32.5f - sqrtf(1056.25f - 2.f * (float)t0));
    if (bm < 0) bm = 0;
    if (bm > NBT - 1) bm = NBT - 1;
    while (bm > 0 && (65 * bm - bm * bm) / 2 > t0) --bm;
    while ((65 * (bm + 1) - (bm + 1) * (bm + 1)) / 2 <= t0) ++bm;
    const int bn = bm + (t0 - (65 * bm - bm * bm) / 2);
    const bool diag = (bm == bn);
    const int Mbase = bm * BT, Nbase = bn * BT;

    f32x4 acc[8][4];
    #pragma unroll
    for (int m = 0; m < 8; ++m)
        #pragma unroll
        for (int n = 0; n < 4; ++n)
            acc[m][n] = (f32x4){0.f, 0.f, 0.f, 0.f};

    // stage one 256x32 matrix tile (2 x global_load_lds of 16B/thread)
    #define STAGE(MAT_BASE, LDSOFF, T, BI) do {                                              \
        const int k0_ = (T) * BKQ;                                                           \
        _Pragma("unroll")                                                                    \
        for (int inst_ = 0; inst_ < 2; ++inst_) {                                            \
            const int q_   = inst_ * 512 + tid;                                              \
            const int row_ = q_ >> 2;                                                        \
            const int cc_  = (q_ & 3) ^ ((q_ >> 4) & 3);                                     \
            const unsigned short* src_ = Xb + (size_t)((MAT_BASE) + row_) * DIM + k0_ + cc_ * 8; \
            unsigned short* dst_ = &lds[BI][(LDSOFF) + (inst_ * 512 + wid * 64) * 8];        \
            __builtin_amdgcn_global_load_lds((const __attribute__((address_space(1))) void*)src_, \
                                             (__attribute__((address_space(3))) void*)dst_, 16, 0, 0); \
        }                                                                                    \
    } while (0)

    // prologue: stage tiles 0,1,2 (24 loads); wait until tile 0 (first 4*2=... 4 loads/tile... ) arrived
    // loads per tile = 4 (A:2 + B:2). Outstanding 12, vmcnt(8) -> tile0's 4 landed.
    STAGE(Mbase, 0, 0, 0); STAGE(Nbase, 8192, 0, 0);
    STAGE(Mbase, 0, 1, 1); STAGE(Nbase, 8192, 1, 1);
    STAGE(Mbase, 0, 2, 2); STAGE(Nbase, 8192, 2, 2);
    asm volatile("s_waitcnt vmcnt(8)" ::: "memory");
    __builtin_amdgcn_s_barrier();
    __builtin_amdgcn_sched_barrier(0);

    for (int t = 0; t < NT; ++t) {
        const int bi = t & 3;
        const unsigned short* Ab = &lds[bi][0];
        const unsigned short* Bb = &lds[bi][8192];
        const bool st = (t + 3 < NT);       // block-uniform
        const int bs = (t + 3) & 3;         // == (t-1)&3: buffer of tile t-1, reads done

        short8 bf[4], af[4];
        // ---- phase 1: B frags + A frags m0..3; stage A(t+3); 16 MFMA
        #pragma unroll
        for (int n = 0; n < 4; ++n) {
            const int row = wn * 64 + n * 16 + l15;
            bf[n] = *(const short8*)(Bb + (row * 4 + swz) * 8);
        }
        #pragma unroll
        for (int m = 0; m < 4; ++m) {
            const int row = wm * 128 + m * 16 + l15;
            af[m] = *(const short8*)(Ab + (row * 4 + swz) * 8);
        }
        if (st) STAGE(Mbase, 0, t + 3, bs);
        __builtin_amdgcn_s_barrier();
        __builtin_amdgcn_s_setprio(1);
        #pragma unroll
        for (int m = 0; m < 4; ++m)
            #pragma unroll
            for (int n = 0; n < 4; ++n)
                acc[m][n] = __builtin_amdgcn_mfma_f32_16x16x32_bf16(af[m], bf[n], acc[m][n], 0, 0, 0);
        __builtin_amdgcn_s_setprio(0);
        __builtin_amdgcn_s_barrier();

        // ---- phase 2: A frags m4..7; stage B(t+3); 16 MFMA
        #pragma unroll
        for (int m = 0; m < 4; ++m) {
            const int row = wm * 128 + (m + 4) * 16 + l15;
            af[m] = *(const short8*)(Ab + (row * 4 + swz) * 8);
        }
        if (st) STAGE(Nbase, 8192, t + 3, bs);
        __builtin_amdgcn_s_barrier();
        __builtin_amdgcn_s_setprio(1);
        #pragma unroll
        for (int m = 0; m < 4; ++m)
            #pragma unroll
            for (int n = 0; n < 4; ++n)
                acc[m + 4][n] = __builtin_amdgcn_mfma_f32_16x16x32_bf16(af[m], bf[n], acc[m + 4][n], 0, 0, 0);
        __builtin_amdgcn_s_setprio(0);

        // ---- tile switch: wait for tile t+1 (leave t+2,t+3 in flight), barrier, pin
        if (t < NT - 3)       asm volatile("s_waitcnt vmcnt(8)" ::: "memory");
        else if (t == NT - 3) asm volatile("s_waitcnt vmcnt(4)" ::: "memory");
        else                  asm volatile("s_waitcnt vmcnt(0)" ::: "memory");
        __builtin_amdgcn_s_barrier();
        __builtin_amdgcn_sched_barrier(0);
    }
    #undef STAGE

    // ---- epilogue. C/D layout: col = l15, row = lk*4 + reg.
    float cv[4];
    #pragma unroll
    for (int n = 0; n < 4; ++n)
        cv[n] = cj[Nbase + wn * 64 + n * 16 + l15];

    // (a) row-max over this wave's 64 cols, combine across wn via LDS
    #pragma unroll
    for (int m = 0; m < 8; ++m) {
        #pragma unroll
        for (int r = 0; r < 4; ++r) {
            const int lrow = wm * 128 + m * 16 + lk * 4 + r;
            float v = -__builtin_inff();
            #pragma unroll
            for (int n = 0; n < 4; ++n) {
                float val = cv[n] - 2.f * acc[m][n][r];
                if (diag && lrow == wn * 64 + n * 16 + l15) val = -__builtin_inff();
                v = fmaxf(v, val);
            }
            #pragma unroll
            for (int off = 8; off >= 1; off >>= 1)
                v = fmaxf(v, __shfl_xor(v, off));
            if (l15 == 0) partrow[wn][lrow] = v;
        }
    }

    // (b) transposed col-max over this wave's 128 rows, combine across wm
    if (!diag) {
        float vt[4];
        #pragma unroll
        for (int n = 0; n < 4; ++n) vt[n] = -__builtin_inff();
        #pragma unroll
        for (int m = 0; m < 8; ++m) {
            #pragma unroll
            for (int r = 0; r < 4; ++r) {
                const float ci = cj[Mbase + wm * 128 + m * 16 + lk * 4 + r];
                #pragma unroll
                for (int n = 0; n < 4; ++n)
                    vt[n] = fmaxf(vt[n], ci - 2.f * acc[m][n][r]);
            }
        }
        #pragma unroll
        for (int n = 0; n < 4; ++n) {
            vt[n] = fmaxf(vt[n], __shfl_xor(vt[n], 16));
            vt[n] = fmaxf(vt[n], __shfl_xor(vt[n], 32));
            if (lk == 0) partcol[wm][wn * 64 + n * 16 + l15] = vt[n];
        }
    }
    __syncthreads();

    if (tid < BT) {
        const float v = fmaxf(fmaxf(partrow[0][tid], partrow[1][tid]),
                              fmaxf(partrow[2][tid], partrow[3][tid]));
        partmax[(size_t)bn * NROWS + Mbase + tid] = v;
    } else if (!diag) {
        const int c = tid - BT;
        partmax[(size_t)bm * NROWS + Nbase + c] = fmaxf(partcol[0][c], partcol[1][c]);
    }
}

// ---------------- kernel 3: per-row finalize + block partial sums ----------------
__global__ void finalize1_kernel(const float* __restrict__ partmax,
                                 const float* __restrict__ basei,
                                 const float* __restrict__ posd,
                                 const int* __restrict__ valid,
                                 float* __restrict__ partials)
{
    const int tid = threadIdx.x;
    const int row = blockIdx.x * 256 + tid;
    float m = -__builtin_inff();
    #pragma unroll 8
    for (int p = 0; p < NBT; ++p)
        m = fmaxf(m, partmax[(size_t)p * NROWS + row]);
    const float d2 = m + basei[row];
    const float mn = sqrtf(fmaxf(d2, 0.f));
    float loss = fmaxf(posd[row] - mn + MARGIN, 0.f);
    float cnt = 1.f;
    if (!valid[row]) { loss = 0.f; cnt = 0.f; }
    #pragma unroll
    for (int off = 32; off >= 1; off >>= 1) {
        loss += __shfl_xor(loss, off);
        cnt  += __shfl_xor(cnt, off);
    }
    __shared__ float sl[4], sc[4];
    const int w = tid >> 6, lane = tid & 63;
    if (lane == 0) { sl[w] = loss; sc[w] = cnt; }
    __syncthreads();
    if (tid == 0) {
        partials[blockIdx.x * 2]     = sl[0] + sl[1] + sl[2] + sl[3];
        partials[blockIdx.x * 2 + 1] = sc[0] + sc[1] + sc[2] + sc[3];
    }
}

// ---------------- kernel 4: final scalar ----------------
__global__ void finalize2_kernel(const float* __restrict__ partials, float* __restrict__ out)
{
    const int tid = threadIdx.x;   // 64 threads
    float l = 0.f, c = 0.f;
    if (tid < 32) { l = partials[tid * 2]; c = partials[tid * 2 + 1]; }
    #pragma unroll
    for (int off = 32; off >= 1; off >>= 1) {
        l += __shfl_xor(l, off);
        c += __shfl_xor(c, off);
    }
    if (tid == 0) out[0] = l / c;
}

extern "C" void kernel_launch(void* const* d_in, const int* in_sizes, int n_in,
                              void* d_out, int out_size, void* d_ws, size_t ws_size,
                              hipStream_t stream)
{
    const float* X = (const float*)d_in[0];   // [8192,1024] f32
    const float* P = (const float*)d_in[1];   // [1024] f32
    float* out = (float*)d_out;
    char* ws = (char*)d_ws;

    unsigned short* Xb = (unsigned short*)ws;                                // 16 MB bf16
    size_t off = (size_t)NROWS * DIM * sizeof(unsigned short);
    float* cj    = (float*)(ws + off);  off += (size_t)NROWS * 4;
    float* basei = (float*)(ws + off);  off += (size_t)NROWS * 4;
    float* posd  = (float*)(ws + off);  off += (size_t)NROWS * 4;
    int*   valid = (int*)(ws + off);    off += (size_t)NROWS * 4;
    float* partmax = (float*)(ws + off); off += (size_t)NBT * NROWS * 4;     // 1 MB
    float* partials = (float*)(ws + off);

    prep_kernel<<<NROWS / 4, 256, 0, stream>>>(X, P, Xb, cj, basei, posd, valid);
    gemm_max_kernel<<<NTRI, 512, 0, stream>>>(Xb, cj, partmax);
    finalize1_kernel<<<NROWS / 256, 256, 0, stream>>>(partmax, basei, posd, valid, partials);
    finalize2_kernel<<<1, 64, 0, stream>>>(partials, out);
}

// Round 4
// 127.751 us; speedup vs baseline: 1.8153x; 1.0790x over previous
//
#include <hip/hip_runtime.h>
#include <hip/hip_bf16.h>

// BatchTripletLoss on MI355X — round 4: m201-class 8-phase inner schedule.
// 256^2 triangular blocks (bn>=bm), BK=64, 8 waves (2M x 4N), 2 dbuf x 4 half-slots,
// per-phase {ds-read, stage quantum, barrier, setprio, 16 MFMA, setprio, barrier},
// counted vmcnt(8) once per K-tile (2-KT prefetch lead), both-sides XOR swizzle.

#define NROWS 8192
#define DIM   1024
#define BT    256
#define BK    64
#define NKT   (DIM / BK)            // 16 K-tiles
#define NBT   (NROWS / BT)          // 32 tile-rows
#define NTRI  (NBT * (NBT + 1) / 2) // 528 blocks

constexpr float EPS = 1e-6f;
constexpr float MARGIN = 0.5f;

typedef __attribute__((ext_vector_type(8))) short short8;
typedef __attribute__((ext_vector_type(4))) float f32x4;

__device__ __forceinline__ unsigned short f2bf_rne(float f) {
    unsigned u = __float_as_uint(f);
    u += 0x7fffu + ((u >> 16) & 1u);
    return (unsigned short)(u >> 16);
}

// ---------------- kernel 1: per-row stats + bf16 conversion ----------------
__global__ void prep_kernel(const float* __restrict__ X, const float* __restrict__ P,
                            unsigned short* __restrict__ Xb,
                            float* __restrict__ cj, float* __restrict__ basei,
                            float* __restrict__ posd, int* __restrict__ valid)
{
    const int tid  = threadIdx.x;
    const int w    = tid >> 6;
    const int lane = tid & 63;
    const int row  = blockIdx.x * 4 + w;
    const float* xr = X + (size_t)row * DIM;

    float sq = 0.f, sm = 0.f, pd = 0.f;
    bool eq = true;
    #pragma unroll
    for (int it = 0; it < 4; ++it) {
        const int idx = it * 256 + lane * 4;
        const float4 x = *(const float4*)(xr + idx);
        const float4 p = *(const float4*)(P + idx);
        sq += x.x*x.x + x.y*x.y + x.z*x.z + x.w*x.w;
        sm += x.x + x.y + x.z + x.w;
        const float d0 = x.x - p.x + EPS, d1 = x.y - p.y + EPS;
        const float d2 = x.z - p.z + EPS, d3 = x.w - p.w + EPS;
        pd += d0*d0 + d1*d1 + d2*d2 + d3*d3;
        eq = eq && (x.x == p.x) && (x.y == p.y) && (x.z == p.z) && (x.w == p.w);
        ushort4 b;
        b.x = f2bf_rne(x.x); b.y = f2bf_rne(x.y); b.z = f2bf_rne(x.z); b.w = f2bf_rne(x.w);
        *(ushort4*)(Xb + (size_t)row * DIM + idx) = b;
    }
    #pragma unroll
    for (int off = 32; off >= 1; off >>= 1) {
        sq += __shfl_xor(sq, off);
        sm += __shfl_xor(sm, off);
        pd += __shfl_xor(pd, off);
    }
    const bool alleq = __all(eq);
    if (lane == 0) {
        cj[row]    = sq - 2.f * EPS * sm;
        basei[row] = sq + 2.f * EPS * sm + (float)DIM * EPS * EPS;
        posd[row]  = sqrtf(pd);
        valid[row] = alleq ? 0 : 1;
    }
}

// ---------------- kernel 2: 8-phase deep-pipelined symmetric GEMM + row/col max ----------------
// LDS half-slot = 128 rows x 64 K bf16 = 1024 chunks of 16B. Swizzle: logical (r,c)
// chunk at phys p = r*8 + (c ^ (r&7)). gload_lds writes phys-linear (thread q -> chunk q),
// so source is pre-permuted: thread q fetches row q>>3, K-chunk (q&7)^((q>>3)&7).
__global__ __launch_bounds__(512, 2) void gemm_max_kernel(
        const unsigned short* __restrict__ Xb,
        const float* __restrict__ cj,
        float* __restrict__ partmax)
{
    // [buf][slot: A0,A1,B0,B1][1024 chunks * 8 ushort]
    __shared__ alignas(16) unsigned short lds[2][4][8192];
    __shared__ float partrow[4][BT];
    __shared__ float partcol[2][BT];

    const int tid  = threadIdx.x;
    const int lane = tid & 63;
    const int wid  = tid >> 6;        // 0..7
    const int wm   = wid >> 2;        // 0..1  (M half: 128 rows)
    const int wn   = wid & 3;         // 0..3  (N quarter: 64 cols)
    const int l15  = lane & 15;
    const int lk   = lane >> 4;       // 0..3
    const int cx0  = lk ^ (l15 & 7);          // K-chunk for ks=0
    const int cx1  = (4 + lk) ^ (l15 & 7);    // ks=1

    // XCD-chunked bijective triangular decode (528 = 8 * 66)
    const int t0 = (blockIdx.x & 7) * (NTRI / 8) + (blockIdx.x >> 3);
    int bm = (int)(32.5f - sqrtf(1056.25f - 2.f * (float)t0));
    if (bm < 0) bm = 0;
    if (bm > NBT - 1) bm = NBT - 1;
    while (bm > 0 && (65 * bm - bm * bm) / 2 > t0) --bm;
    while ((65 * (bm + 1) - (bm + 1) * (bm + 1)) / 2 <= t0) ++bm;
    const int bn = bm + (t0 - (65 * bm - bm * bm) / 2);
    const bool diag = (bm == bn);
    const int Mbase = bm * BT, Nbase = bn * BT;

    f32x4 acc[8][4];
    #pragma unroll
    for (int m = 0; m < 8; ++m)
        #pragma unroll
        for (int n = 0; n < 4; ++n)
            acc[m][n] = (f32x4){0.f, 0.f, 0.f, 0.f};

    // stage one half-slot quantum (128 rows x 64 K): 2 x global_load_lds(16B)
    #define STAGE(BUF, SLOT, GBASE, KT) do {                                                  \
        _Pragma("unroll")                                                                     \
        for (int inst_ = 0; inst_ < 2; ++inst_) {                                             \
            const int q_ = inst_ * 512 + tid;                                                 \
            const int r_ = q_ >> 3;                                                           \
            const int c_ = (q_ & 7) ^ (r_ & 7);                                               \
            const unsigned short* src_ = Xb + (size_t)((GBASE) + r_) * DIM + (KT) * BK + c_ * 8; \
            unsigned short* dst_ = &lds[BUF][SLOT][(inst_ * 512 + wid * 64) * 8];             \
            __builtin_amdgcn_global_load_lds((const __attribute__((address_space(1))) void*)src_, \
                                             (__attribute__((address_space(3))) void*)dst_, 16, 0, 0); \
        }                                                                                     \
    } while (0)

    // prologue: stage kt0 (8 loads) then kt1 (8 loads); vmcnt(8) -> kt0 landed
    STAGE(0, 0, Mbase, 0); STAGE(0, 1, Mbase + 128, 0);
    STAGE(0, 2, Nbase, 0); STAGE(0, 3, Nbase + 128, 0);
    STAGE(1, 0, Mbase, 1); STAGE(1, 1, Mbase + 128, 1);
    STAGE(1, 2, Nbase, 1); STAGE(1, 3, Nbase + 128, 1);
    asm volatile("s_waitcnt vmcnt(8)" ::: "memory");
    __builtin_amdgcn_s_barrier();
    __builtin_amdgcn_sched_barrier(0);

    const int cl0 = (wn & 1) * 64;          // wave's col base within its B-half

    for (int kt = 0; kt < NKT; ++kt) {
        const int b = kt & 1;
        const unsigned short* Ah = &lds[b][wm][0];
        const unsigned short* Bh = &lds[b][2 + (wn >> 1)][0];
        const bool st = (kt + 2 < NKT);     // block-uniform
        const int kp = kt + 2;
        short8 af[8], bf0[4], bf1[4];

        // ---- P0: read A rh0 (8) + B ch0 (4); MFMA quad(rh0,ch0)
        #pragma unroll
        for (int mt = 0; mt < 4; ++mt) {
            af[mt * 2]     = *(const short8*)(Ah + (mt * 16 + l15) * 64 + cx0 * 8);
            af[mt * 2 + 1] = *(const short8*)(Ah + (mt * 16 + l15) * 64 + cx1 * 8);
        }
        #pragma unroll
        for (int nt = 0; nt < 2; ++nt) {
            bf0[nt * 2]     = *(const short8*)(Bh + (cl0 + nt * 16 + l15) * 64 + cx0 * 8);
            bf0[nt * 2 + 1] = *(const short8*)(Bh + (cl0 + nt * 16 + l15) * 64 + cx1 * 8);
        }
        __builtin_amdgcn_s_barrier();
        __builtin_amdgcn_s_setprio(1);
        #pragma unroll
        for (int mt = 0; mt < 4; ++mt)
            #pragma unroll
            for (int nt = 0; nt < 2; ++nt)
                #pragma unroll
                for (int ks = 0; ks < 2; ++ks)
                    acc[mt][nt] = __builtin_amdgcn_mfma_f32_16x16x32_bf16(af[mt*2+ks], bf0[nt*2+ks], acc[mt][nt], 0, 0, 0);
        __builtin_amdgcn_s_setprio(0);
        __builtin_amdgcn_s_barrier();

        // ---- P1: read B ch1 (4); stage B0(kt+2); MFMA quad(rh0,ch1)
        #pragma unroll
        for (int nt = 0; nt < 2; ++nt) {
            bf1[nt * 2]     = *(const short8*)(Bh + (cl0 + 32 + nt * 16 + l15) * 64 + cx0 * 8);
            bf1[nt * 2 + 1] = *(const short8*)(Bh + (cl0 + 32 + nt * 16 + l15) * 64 + cx1 * 8);
        }
        if (st) STAGE(b, 2, Nbase, kp);
        __builtin_amdgcn_s_barrier();
        __builtin_amdgcn_s_setprio(1);
        #pragma unroll
        for (int mt = 0; mt < 4; ++mt)
            #pragma unroll
            for (int nt = 0; nt < 2; ++nt)
                #pragma unroll
                for (int ks = 0; ks < 2; ++ks)
                    acc[mt][2+nt] = __builtin_amdgcn_mfma_f32_16x16x32_bf16(af[mt*2+ks], bf1[nt*2+ks], acc[mt][2+nt], 0, 0, 0);
        __builtin_amdgcn_s_setprio(0);
        __builtin_amdgcn_s_barrier();

        // ---- P2: read A rh1 (8); stage B1(kt+2); MFMA quad(rh1,ch1)
        #pragma unroll
        for (int mt = 0; mt < 4; ++mt) {
            af[mt * 2]     = *(const short8*)(Ah + (64 + mt * 16 + l15) * 64 + cx0 * 8);
            af[mt * 2 + 1] = *(const short8*)(Ah + (64 + mt * 16 + l15) * 64 + cx1 * 8);
        }
        if (st) STAGE(b, 3, Nbase + 128, kp);
        __builtin_amdgcn_s_barrier();
        __builtin_amdgcn_s_setprio(1);
        #pragma unroll
        for (int mt = 0; mt < 4; ++mt)
            #pragma unroll
            for (int nt = 0; nt < 2; ++nt)
                #pragma unroll
                for (int ks = 0; ks < 2; ++ks)
                    acc[4+mt][2+nt] = __builtin_amdgcn_mfma_f32_16x16x32_bf16(af[mt*2+ks], bf1[nt*2+ks], acc[4+mt][2+nt], 0, 0, 0);
        __builtin_amdgcn_s_setprio(0);
        __builtin_amdgcn_s_barrier();

        // ---- P3: stage A0,A1(kt+2); MFMA quad(rh1,ch0) — all operands in regs, no pre-barrier
        if (st) { STAGE(b, 0, Mbase, kp); STAGE(b, 1, Mbase + 128, kp); }
        __builtin_amdgcn_s_setprio(1);
        #pragma unroll
        for (int mt = 0; mt < 4; ++mt)
            #pragma unroll
            for (int nt = 0; nt < 2; ++nt)
                #pragma unroll
                for (int ks = 0; ks < 2; ++ks)
                    acc[4+mt][nt] = __builtin_amdgcn_mfma_f32_16x16x32_bf16(af[mt*2+ks], bf0[nt*2+ks], acc[4+mt][nt], 0, 0, 0);
        __builtin_amdgcn_s_setprio(0);

        // tile switch: ensure kt+1 landed; keep kt+2's 8 loads in flight
        if (kt < NKT - 2)       asm volatile("s_waitcnt vmcnt(8)" ::: "memory");
        else if (kt == NKT - 2) asm volatile("s_waitcnt vmcnt(0)" ::: "memory");
        __builtin_amdgcn_s_barrier();
        __builtin_amdgcn_sched_barrier(0);
    }
    #undef STAGE

    // ---- epilogue. C/D layout: col = l15, row = lk*4 + reg. acc[m][n]: row m*16, col n*16
    float cv[4];
    #pragma unroll
    for (int n = 0; n < 4; ++n)
        cv[n] = cj[Nbase + wn * 64 + n * 16 + l15];

    // (a) row-max over this wave's 64 cols, combine across wn via LDS
    #pragma unroll
    for (int m = 0; m < 8; ++m) {
        #pragma unroll
        for (int r = 0; r < 4; ++r) {
            const int lrow = wm * 128 + m * 16 + lk * 4 + r;
            float v = -__builtin_inff();
            #pragma unroll
            for (int n = 0; n < 4; ++n) {
                float val = cv[n] - 2.f * acc[m][n][r];
                if (diag && lrow == wn * 64 + n * 16 + l15) val = -__builtin_inff();
                v = fmaxf(v, val);
            }
            #pragma unroll
            for (int off = 8; off >= 1; off >>= 1)
                v = fmaxf(v, __shfl_xor(v, off));
            if (l15 == 0) partrow[wn][lrow] = v;
        }
    }

    // (b) transposed col-max over this wave's 128 rows, combine across wm
    if (!diag) {
        float vt[4];
        #pragma unroll
        for (int n = 0; n < 4; ++n) vt[n] = -__builtin_inff();
        #pragma unroll
        for (int m = 0; m < 8; ++m) {
            #pragma unroll
            for (int r = 0; r < 4; ++r) {
                const float ci = cj[Mbase + wm * 128 + m * 16 + lk * 4 + r];
                #pragma unroll
                for (int n = 0; n < 4; ++n)
                    vt[n] = fmaxf(vt[n], ci - 2.f * acc[m][n][r]);
            }
        }
        #pragma unroll
        for (int n = 0; n < 4; ++n) {
            vt[n] = fmaxf(vt[n], __shfl_xor(vt[n], 16));
            vt[n] = fmaxf(vt[n], __shfl_xor(vt[n], 32));
            if (lk == 0) partcol[wm][wn * 64 + n * 16 + l15] = vt[n];
        }
    }
    __syncthreads();

    if (tid < BT) {
        const float v = fmaxf(fmaxf(partrow[0][tid], partrow[1][tid]),
                              fmaxf(partrow[2][tid], partrow[3][tid]));
        partmax[(size_t)bn * NROWS + Mbase + tid] = v;
    } else if (!diag) {
        const int c = tid - BT;
        partmax[(size_t)bm * NROWS + Nbase + c] = fmaxf(partcol[0][c], partcol[1][c]);
    }
}

// ---------------- kernel 3: per-row finalize + block partial sums ----------------
__global__ void finalize1_kernel(const float* __restrict__ partmax,
                                 const float* __restrict__ basei,
                                 const float* __restrict__ posd,
                                 const int* __restrict__ valid,
                                 float* __restrict__ partials)
{
    const int tid = threadIdx.x;
    const int row = blockIdx.x * 256 + tid;
    float m = -__builtin_inff();
    #pragma unroll 8
    for (int p = 0; p < NBT; ++p)
        m = fmaxf(m, partmax[(size_t)p * NROWS + row]);
    const float d2 = m + basei[row];
    const float mn = sqrtf(fmaxf(d2, 0.f));
    float loss = fmaxf(posd[row] - mn + MARGIN, 0.f);
    float cnt = 1.f;
    if (!valid[row]) { loss = 0.f; cnt = 0.f; }
    #pragma unroll
    for (int off = 32; off >= 1; off >>= 1) {
        loss += __shfl_xor(loss, off);
        cnt  += __shfl_xor(cnt, off);
    }
    __shared__ float sl[4], sc[4];
    const int w = tid >> 6, lane = tid & 63;
    if (lane == 0) { sl[w] = loss; sc[w] = cnt; }
    __syncthreads();
    if (tid == 0) {
        partials[blockIdx.x * 2]     = sl[0] + sl[1] + sl[2] + sl[3];
        partials[blockIdx.x * 2 + 1] = sc[0] + sc[1] + sc[2] + sc[3];
    }
}

// ---------------- kernel 4: final scalar ----------------
__global__ void finalize2_kernel(const float* __restrict__ partials, float* __restrict__ out)
{
    const int tid = threadIdx.x;   // 64 threads
    float l = 0.f, c = 0.f;
    if (tid < 32) { l = partials[tid * 2]; c = partials[tid * 2 + 1]; }
    #pragma unroll
    for (int off = 32; off >= 1; off >>= 1) {
        l += __shfl_xor(l, off);
        c += __shfl_xor(c, off);
    }
    if (tid == 0) out[0] = l / c;
}

extern "C" void kernel_launch(void* const* d_in, const int* in_sizes, int n_in,
                              void* d_out, int out_size, void* d_ws, size_t ws_size,
                              hipStream_t stream)
{
    const float* X = (const float*)d_in[0];   // [8192,1024] f32
    const float* P = (const float*)d_in[1];   // [1024] f32
    float* out = (float*)d_out;
    char* ws = (char*)d_ws;

    unsigned short* Xb = (unsigned short*)ws;                                // 16 MB bf16
    size_t off = (size_t)NROWS * DIM * sizeof(unsigned short);
    float* cj    = (float*)(ws + off);  off += (size_t)NROWS * 4;
    float* basei = (float*)(ws + off);  off += (size_t)NROWS * 4;
    float* posd  = (float*)(ws + off);  off += (size_t)NROWS * 4;
    int*   valid = (int*)(ws + off);    off += (size_t)NROWS * 4;
    float* partmax = (float*)(ws + off); off += (size_t)NBT * NROWS * 4;     // 1 MB
    float* partials = (float*)(ws + off);

    prep_kernel<<<NROWS / 4, 256, 0, stream>>>(X, P, Xb, cj, basei, posd, valid);
    gemm_max_kernel<<<NTRI, 512, 0, stream>>>(Xb, cj, partmax);
    finalize1_kernel<<<NROWS / 256, 256, 0, stream>>>(partmax, basei, posd, valid, partials);
    finalize2_kernel<<<1, 64, 0, stream>>>(partials, out);
}